// Round 1
// 1879.974 us; speedup vs baseline: 1.1123x; 1.1123x over previous
//
#include <hip/hip_runtime.h>
#include <cstdint>
#include <cstddef>

// ---------------------------------------------------------------------------
// QRNN 2-bit forward, exact ternary-integer formulation.
// flags[0]=1 -> floats are f32 (else bf16); flags[1]=1 -> text is int64.
// Ternary vectors (len 1024) bit-packed as 32 u64: [2i]=plus, [2i+1]=nonzero.
// As uint4 i: (p.lo, p.hi, z.lo, z.hi) for elements 64i..64i+63.
// dot: both=hz&wz; neg=both&(hp^wp); k=popc(both)-2*popc(neg)
// Decision v = k*0.1+bias vs +-0.5 is monotone in k -> precomputed integer
// thresholds kp/km reproduce the f64 predicate bit-exactly.
//
// R-pipeline: the two layer recurrences + layer-1 bitgemm run as a fused
// 3-stage pipeline (k_pipe, 192 blocks = 64 A + 64 B + 64 C):
//   A = layer-0 recur (produces x_t, publishes flagsA every 4 steps)
//   B = layer-1 input bit-GEMM (x_t -> n_t in-place into nbuf, flagsB/step)
//   C = layer-1 recur (consumes n_t, speculative prefetch of n_{t+1})
// Handoff protocol: producer side = plain stores + __syncthreads (vmcnt(0)
// drain) + thread-0 __ATOMIC_RELEASE/agent store (emits L2 writeback).
// Consumer side = RELAXED agent-scope loads (sc0/sc1 bypass stale L1/L2);
// data loads are control-dependent on the flag value => ordered without an
// acquire waitcnt on the critical path. Dependency graph is acyclic (A never
// waits) and 192 blocks x 16 waves @128-VGPR cap = 1 block/CU, all
// co-resident on 256 CUs => no deadlock.
// nbuf aliasing: B writes slot (b,t) only after flagsA >= t+1, i.e. after A's
// last (prefetch) read of slot t; C reads slot t only after flagsB >= t+1.
//
// k_recur-core design (stages A/C): weights live in VGPRs/AGPRs (64 words x
// 1024 threads = 256 KB/CU); h broadcast via same-address ds_read_b128.
// __launch_bounds__(1024,4) => 1 block/CU => 128-VGPR cap: REQUIRED so the
// 64 weight words stay in the register file (no scratch spill).
// ---------------------------------------------------------------------------

static __device__ __forceinline__ float bf2f(unsigned short b) {
  return __uint_as_float(((unsigned)b) << 16);
}
static __device__ __forceinline__ unsigned short f2bf(float f) {
  unsigned u = __float_as_uint(f);
  u = (u + 0x7FFFu + ((u >> 16) & 1u)) >> 16;  // RNE
  return (unsigned short)u;
}
static __device__ __forceinline__ float loadw(const void* p, size_t i, int isf32) {
  return isf32 ? ((const float*)p)[i] : bf2f(((const unsigned short*)p)[i]);
}

__global__ __launch_bounds__(256) void k_detect(const unsigned short* __restrict__ embu,
                                                const int* __restrict__ text,
                                                int* __restrict__ flags) {
  int i = blockIdx.x * 256 + threadIdx.x;  // 65536 u16 samples: valid in either layout
  unsigned e = (embu[i] >> 7) & 0xFFu;     // bf16-view exponent field
  unsigned long long b = __ballot(e >= 127u);
  if ((threadIdx.x & 63) == 0 && b) atomicOr(&flags[0], 1);
  if (blockIdx.x == 0 && threadIdx.x == 0) {
    int allz = 1;
    for (int j = 0; j < 32; j++)
      if (text[2 * j + 1] != 0) allz = 0;   // first 256 B: valid in either layout
    flags[1] = allz;
  }
}

// vectorized max|emb|
__global__ __launch_bounds__(256) void k_maxabs(const uint4* __restrict__ w,
                                                const int* __restrict__ flags,
                                                unsigned* __restrict__ out) {
  int isf32 = flags[0];
  int n16 = isf32 ? 7680000 : 3840000;  // 30720000 elems / (4 or 8 per uint4)
  float mf = 0.f;
  unsigned mb = 0;
  int i = blockIdx.x * blockDim.x + threadIdx.x;
  int stride = gridDim.x * blockDim.x;
  if (isf32) {
    for (; i < n16; i += stride) {
      uint4 v = w[i];
      mf = fmaxf(mf, fabsf(__uint_as_float(v.x)));
      mf = fmaxf(mf, fabsf(__uint_as_float(v.y)));
      mf = fmaxf(mf, fabsf(__uint_as_float(v.z)));
      mf = fmaxf(mf, fabsf(__uint_as_float(v.w)));
    }
  } else {
    for (; i < n16; i += stride) {
      uint4 v = w[i];
      unsigned a;
      a = v.x & 0x7FFF7FFFu; mb = max(mb, a & 0xFFFFu); mb = max(mb, a >> 16);
      a = v.y & 0x7FFF7FFFu; mb = max(mb, a & 0xFFFFu); mb = max(mb, a >> 16);
      a = v.z & 0x7FFF7FFFu; mb = max(mb, a & 0xFFFFu); mb = max(mb, a >> 16);
      a = v.w & 0x7FFF7FFFu; mb = max(mb, a & 0xFFFFu); mb = max(mb, a >> 16);
    }
    mf = bf2f((unsigned short)mb);
  }
  for (int off = 32; off > 0; off >>= 1) mf = fmaxf(mf, __shfl_down(mf, off));
  __shared__ float red[4];
  if ((threadIdx.x & 63) == 0) red[threadIdx.x >> 6] = mf;
  __syncthreads();
  if (threadIdx.x == 0) {
    float b = fmaxf(fmaxf(red[0], red[1]), fmaxf(red[2], red[3]));
    atomicMax(out, __float_as_uint(b));  // b >= 0: bit pattern order-monotone
  }
}

__global__ __launch_bounds__(1024) void k_tern_rows(
    const void* __restrict__ Wih, const void* __restrict__ Whh,
    const void* __restrict__ fcw, const int* __restrict__ flags,
    unsigned long long* __restrict__ wim, unsigned long long* __restrict__ whm,
    unsigned long long* __restrict__ fcm) {
  int isf32 = flags[0];
  int b = blockIdx.x;  // 0..4099
  const void* src;
  size_t rowoff;
  unsigned long long* dst;
  if (b < 2048)      { src = Wih; rowoff = (size_t)b * 1024; dst = wim + (size_t)b * 32; }
  else if (b < 4096) { int r = b - 2048; src = Whh; rowoff = (size_t)r * 1024; dst = whm + (size_t)r * 32; }
  else               { int r = b - 4096; src = fcw; rowoff = (size_t)r * 1024; dst = fcm + (size_t)r * 32; }
  double w = (double)loadw(src, rowoff + threadIdx.x, isf32);
  unsigned long long bp = __ballot(w > 0.05);   // THR*W_SCALE, exact f64
  unsigned long long bm = __ballot(w < -0.05);
  if ((threadIdx.x & 63) == 0) {
    int wv = threadIdx.x >> 6;
    dst[2 * wv] = bp;
    dst[2 * wv + 1] = bp | bm;
  }
}

__global__ __launch_bounds__(1024) void k_embed(const int* __restrict__ text,
    const void* __restrict__ emb, const int* __restrict__ flags,
    const unsigned* __restrict__ mab, unsigned long long* __restrict__ x0) {
  int isf32 = flags[0], i64 = flags[1];
  int bt = blockIdx.x;
  long long tok = i64 ? ((const long long*)text)[bt] : (long long)text[bt];
  double ma = (double)__uint_as_float(*mab);
  float s = (float)exp2(ceil(log2(ma)));           // pow-2 scale (int_max = 1)
  float inv_s = 1.0f / s;                          // exact (pow-2)
  float w = loadw(emb, (size_t)tok * 1024 + threadIdx.x, isf32);
  float q = rintf(w * inv_s);                      // exact mul, half-even
  q = fminf(fmaxf(q, -2.0f), 1.0f);                // clip [-2, 1] (bw = 2)
  float val = q * s;                               // exact
  int code = (val > 0.5f) ? 1 : ((val < -0.5f) ? -1 : 0);
  unsigned long long bp = __ballot(code == 1);
  unsigned long long bm = __ballot(code == -1);
  if ((threadIdx.x & 63) == 0) {
    int wv = threadIdx.x >> 6;
    x0[(size_t)bt * 32 + 2 * wv] = bp;
    x0[(size_t)bt * 32 + 2 * wv + 1] = bp | bm;
  }
}

// ---- bit-GEMM (layer-0 pre-pass): n[bt][r] = <x_row[bt], Wi_row[r]> -------
__global__ __launch_bounds__(256, 4) void k_bitgemm(const unsigned long long* __restrict__ xm,
    const unsigned long long* __restrict__ wim, short* __restrict__ nbuf) {
  __shared__ __align__(16) uint4 lx[64 * 16];  // [bt][i] = (p.lo,p.hi,z.lo,z.hi)
  __shared__ unsigned any[64];
  int tid = threadIdx.x;
  int bt0 = blockIdx.x * 64;
  int r = blockIdx.y * 256 + tid;
  unsigned wplo[16], wphi[16], wzlo[16], wzhi[16];
  const uint4* wrow = (const uint4*)(wim + (size_t)r * 32);
#pragma unroll
  for (int i = 0; i < 16; i++) {
    uint4 w4 = wrow[i];
    wplo[i] = w4.x; wphi[i] = w4.y; wzlo[i] = w4.z; wzhi[i] = w4.w;
  }
  if (tid < 64) any[tid] = 0;
  __syncthreads();
  unsigned accor = 0;
#pragma unroll
  for (int i = 0; i < 4; i++) {
    int idx = tid * 4 + i;  // 0..1023 uint4 slots, straight copy
    uint4 v = ((const uint4*)(xm + (size_t)bt0 * 32))[idx];
    lx[idx] = v;
    accor |= v.z | v.w;  // nonzero-mask halves
  }
  if (accor) atomicOr(&any[tid >> 2], 1u);  // 4 threads per bt row
  __syncthreads();
  for (int bt = 0; bt < 64; bt++) {
    int k = 0;
    if (any[bt]) {
      const uint4* hx = lx + bt * 16;
      int sb = 0, sn = 0;
#pragma unroll
      for (int i = 0; i < 16; i++) {
        uint4 h = hx[i];  // broadcast ds_read_b128
        unsigned blo = h.z & wzlo[i];
        unsigned bhi = h.w & wzhi[i];
        unsigned nlo = (h.x ^ wplo[i]) & blo;
        unsigned nhi = (h.y ^ wphi[i]) & bhi;
        sb += __popc(blo) + __popc(bhi);
        sn += __popc(nlo) + __popc(nhi);
      }
      k = sb - 2 * sn;
    }
    nbuf[(size_t)(bt0 + bt) * 1024 + r] = (short)k;
  }
}

// ---- fused 3-stage pipeline ----------------------------------------------
#define FLAG_STRIDE 16  // one flag per 64 B to avoid line contention

// ROLE 0 = layer-0 recur (producer of x_t); ROLE 2 = layer-1 recur (consumer)
template <int ROLE>
static __device__ __forceinline__ void recur_stage(
    uint4 (*shb)[16], const short* nbuf,
    const unsigned long long* __restrict__ whm,
    const void* __restrict__ bih, const void* __restrict__ bhh,
    int isf32, int layer, int b, int r,
    unsigned long long* xrow,              // ROLE 0 only
    int* flagsA, int* flagsB,
    unsigned long long* __restrict__ hidm) {
  unsigned wplo[16], wphi[16], wzlo[16], wzhi[16];
  const uint4* wrow = (const uint4*)(whm + (size_t)(layer * 1024 + r) * 32);
#pragma unroll
  for (int i = 0; i < 16; i++) {
    uint4 w4 = wrow[i];
    wplo[i] = w4.x; wphi[i] = w4.y; wzlo[i] = w4.z; wzhi[i] = w4.w;
  }
  size_t boff = (size_t)layer * 1024 + r;
  double bias = (double)loadw(bih, boff, isf32) + (double)loadw(bhh, boff, isf32);
  // exact integer thresholds reproducing the f64 predicate
  int kp = (int)ceil((0.5 - bias) * 10.0);
  while ((double)kp * 0.1 + bias <= 0.5) kp++;
  while ((double)(kp - 1) * 0.1 + bias > 0.5) kp--;
  int km = (int)floor((-0.5 - bias) * 10.0);
  while ((double)km * 0.1 + bias >= -0.5) km--;
  while ((double)(km + 1) * 0.1 + bias < -0.5) km++;

  if (r < 32) ((unsigned long long*)shb)[r] = 0;  // zero buffer 0
  const short* nrow = nbuf + (size_t)b * 512 * 1024 + r;
  int wv = r >> 6;
  bool l0 = (r & 63) == 0;
  int nin;
  if (ROLE == 0) {
    nin = (int)nrow[0];  // t = 0 preload (pre-pass bitgemm data: plain load ok)
  } else {
    // wait for B's slot 0; relaxed agent loads bypass stale L1/L2, data load
    // is control-dependent on the flag value => ordered.
    while (__hip_atomic_load(flagsB + b * FLAG_STRIDE, __ATOMIC_RELAXED,
                             __HIP_MEMORY_SCOPE_AGENT) < 1) {}
    nin = (int)__hip_atomic_load(nrow, __ATOMIC_RELAXED, __HIP_MEMORY_SCOPE_AGENT);
  }
  __syncthreads();
  int pb = 0;
  for (int t = 0; t < 512; t++) {
    int fl = 0;
    if (ROLE == 2 && t < 511)  // issue early; value consumed mid-dot
      fl = __hip_atomic_load(flagsB + b * FLAG_STRIDE, __ATOMIC_RELAXED,
                             __HIP_MEMORY_SCOPE_AGENT);
    const uint4* Hq = shb[pb];
    int sb = 0, sn = 0;
#pragma unroll
    for (int i = 0; i < 8; i++) {
      uint4 h = Hq[i];  // broadcast ds_read_b128
      unsigned blo = h.z & wzlo[i];
      unsigned bhi = h.w & wzhi[i];
      unsigned nlo = (h.x ^ wplo[i]) & blo;
      unsigned nhi = (h.y ^ wphi[i]) & bhi;
      sb += __popc(blo) + __popc(bhi);
      sn += __popc(nlo) + __popc(nhi);
    }
    // mid-dot: prefetch next-step input so its latency hides under iters 8..15
    int nin_next = 0;
    bool got = true;
    if (ROLE == 0) {
      if (t < 511) nin_next = (int)nrow[(size_t)(t + 1) * 1024];
    } else if (t < 511) {
      got = (fl >= t + 2);
      if (got)
        nin_next = (int)__hip_atomic_load(nrow + (size_t)(t + 1) * 1024,
                                          __ATOMIC_RELAXED, __HIP_MEMORY_SCOPE_AGENT);
    }
#pragma unroll
    for (int i = 8; i < 16; i++) {
      uint4 h = Hq[i];
      unsigned blo = h.z & wzlo[i];
      unsigned bhi = h.w & wzhi[i];
      unsigned nlo = (h.x ^ wplo[i]) & blo;
      unsigned nhi = (h.y ^ wphi[i]) & bhi;
      sb += __popc(blo) + __popc(bhi);
      sn += __popc(nlo) + __popc(nhi);
    }
    int k = nin + sb - 2 * sn;
    unsigned long long bp = __ballot(k >= kp);
    unsigned long long bm = __ballot(k <= km);
    unsigned long long bz = bp | bm;
    if (l0) {
      uint4 o;
      o.x = (unsigned)bp; o.y = (unsigned)(bp >> 32);
      o.z = (unsigned)bz; o.w = (unsigned)(bz >> 32);
      shb[pb ^ 1][wv] = o;
      if (ROLE == 0) ((uint4*)(xrow + (size_t)t * 32))[wv] = o;
    }
    if (ROLE == 2 && !got && t < 511) {  // cold path: pipeline fill only
      while (__hip_atomic_load(flagsB + b * FLAG_STRIDE, __ATOMIC_RELAXED,
                               __HIP_MEMORY_SCOPE_AGENT) < t + 2) {}
      nin_next = (int)__hip_atomic_load(nrow + (size_t)(t + 1) * 1024,
                                        __ATOMIC_RELAXED, __HIP_MEMORY_SCOPE_AGENT);
    }
    __syncthreads();  // Hbuf flip visible; all waves' x-stores drained (vmcnt 0)
    if (ROLE == 0 && r == 0 && (t & 3) == 3)  // publish 4 steps at a time
      __hip_atomic_store(flagsA + b * FLAG_STRIDE, t + 1, __ATOMIC_RELEASE,
                         __HIP_MEMORY_SCOPE_AGENT);
    pb ^= 1;
    nin = nin_next;
  }
  if (r < 16) {  // final h is in shb[pb]
    uint4 h = shb[pb][r];
    size_t ho = (size_t)(layer * 64 + b) * 32;
    hidm[ho + 2 * r]     = ((unsigned long long)h.y << 32) | h.x;
    hidm[ho + 2 * r + 1] = ((unsigned long long)h.w << 32) | h.z;
  }
}

__global__ __launch_bounds__(1024, 4) void k_pipe(
    short* nbuf, unsigned long long* x0,
    const unsigned long long* __restrict__ wim,
    const unsigned long long* __restrict__ whm,
    const void* __restrict__ bih, const void* __restrict__ bhh,
    const int* __restrict__ flags, int* flagsA, int* flagsB,
    unsigned long long* __restrict__ hidm) {
  __shared__ __align__(16) uint4 shb[2][16];
  int role = blockIdx.x % 3;  // interleave roles across XCDs
  int b = blockIdx.x / 3;
  int r = threadIdx.x;
  int isf32 = flags[0];
  if (role == 0) {
    recur_stage<0>(shb, nbuf, whm, bih, bhh, isf32, 0, b, r,
                   x0 + (size_t)b * 512 * 32, flagsA, flagsB, hidm);
  } else if (role == 1) {
    // ---- stage B: layer-1 input bit-GEMM, trailing A by <= 4 steps --------
    unsigned wplo[16], wphi[16], wzlo[16], wzhi[16];
    const uint4* wrow = (const uint4*)(wim + (size_t)(1024 + r) * 32);
#pragma unroll
    for (int i = 0; i < 16; i++) {
      uint4 w4 = wrow[i];
      wplo[i] = w4.x; wphi[i] = w4.y; wzlo[i] = w4.z; wzhi[i] = w4.w;
    }
    const unsigned long long* xsrc = x0 + (size_t)b * 512 * 32;
    short* nout = nbuf + (size_t)b * 512 * 1024 + r;
    for (int t = 0; t < 512; t++) {
      if (r < 64) {  // wave 0 spins; relaxed agent load bypasses stale caches
        while (__hip_atomic_load(flagsA + b * FLAG_STRIDE, __ATOMIC_RELAXED,
                                 __HIP_MEMORY_SCOPE_AGENT) < t + 1) {}
      }
      if (r < 32) {  // control-dependent on spin exit => ordered after flag
        unsigned long long v = __hip_atomic_load(xsrc + (size_t)t * 32 + r,
                                                 __ATOMIC_RELAXED,
                                                 __HIP_MEMORY_SCOPE_AGENT);
        ((unsigned long long*)(shb[t & 1]))[r] = v;
      }
      __syncthreads();
      const uint4* hx = shb[t & 1];
      int sb = 0, sn = 0;
#pragma unroll
      for (int i = 0; i < 16; i++) {
        uint4 h = hx[i];  // broadcast ds_read_b128
        unsigned blo = h.z & wzlo[i];
        unsigned bhi = h.w & wzhi[i];
        unsigned nlo = (h.x ^ wplo[i]) & blo;
        unsigned nhi = (h.y ^ wphi[i]) & bhi;
        sb += __popc(blo) + __popc(bhi);
        sn += __popc(nlo) + __popc(nhi);
      }
      nout[(size_t)t * 1024] = (short)(sb - 2 * sn);
      __syncthreads();  // all waves' n-stores drained (vmcnt 0 before barrier)
      if (r == 0)
        __hip_atomic_store(flagsB + b * FLAG_STRIDE, t + 1, __ATOMIC_RELEASE,
                           __HIP_MEMORY_SCOPE_AGENT);
    }
  } else {
    recur_stage<2>(shb, nbuf, whm, bih, bhh, isf32, 1, b, r,
                   (unsigned long long*)0, flagsA, flagsB, hidm);
  }
}

__global__ __launch_bounds__(64) void k_fc(const unsigned long long* __restrict__ hidm,
    const unsigned long long* __restrict__ fcm, const int* __restrict__ flags,
    void* __restrict__ out) {
  int isf32 = flags[0];
  int lb = blockIdx.x, lane = threadIdx.x;
  unsigned long long hp = 0, hz = 0;
  if (lane < 16) {
    hp = hidm[lb * 32 + 2 * lane];
    hz = hidm[lb * 32 + 2 * lane + 1];
  }
#pragma unroll
  for (int o = 0; o < 4; o++) {
    int k = 0;
    if (lane < 16) {
      unsigned long long wp = fcm[o * 32 + 2 * lane], wz = fcm[o * 32 + 2 * lane + 1];
      unsigned long long both = hz & wz;
      unsigned long long neg = both & (hp ^ wp);
      k = __popcll(both) - 2 * __popcll(neg);
    }
    for (int off = 8; off > 0; off >>= 1) k += __shfl_down(k, off);
    if (lane == 0) {
      float v = (float)((double)k * 0.1);
      if (isf32) ((float*)out)[lb * 4 + o] = v;
      else       ((unsigned short*)out)[lb * 4 + o] = f2bf(v);
    }
  }
}

extern "C" void kernel_launch(void* const* d_in, const int* in_sizes, int n_in,
                              void* d_out, int out_size, void* d_ws, size_t ws_size,
                              hipStream_t stream) {
  (void)in_sizes; (void)n_in; (void)out_size; (void)ws_size;
  const int* text = (const int*)d_in[0];
  // d_in[1] text_lengths: unused by the reference
  const void* emb = d_in[2];
  const void* Wih = d_in[3];
  const void* Whh = d_in[4];
  const void* bih = d_in[5];
  const void* bhh = d_in[6];
  const void* fcw = d_in[7];

  // workspace layout (~73 MB)
  char* ws = (char*)d_ws;
  int* flags = (int*)(ws);
  unsigned* mab = (unsigned*)(ws + 64);
  int* flagsA = (int*)(ws + 1024);   // 64 flags, stride 16 ints (4 KB)
  int* flagsB = (int*)(ws + 5120);   // 64 flags, stride 16 ints (4 KB)
  size_t off = 16384;
  unsigned long long* x0 = (unsigned long long*)(ws + off);  off += (size_t)32768 * 256;
  unsigned long long* wim = (unsigned long long*)(ws + off); off += (size_t)2048 * 256;
  unsigned long long* whm = (unsigned long long*)(ws + off); off += (size_t)2048 * 256;
  unsigned long long* fcm = (unsigned long long*)(ws + off); off += (size_t)4 * 256;
  unsigned long long* hidm = (unsigned long long*)(ws + off); off += (size_t)128 * 256;
  short* nbuf = (short*)(ws + off);                          off += (size_t)32768 * 1024 * 2;

  hipMemsetAsync(ws, 0, 16384, stream);  // flags, mab, flagsA, flagsB
  k_detect<<<256, 256, 0, stream>>>((const unsigned short*)emb, text, flags);
  k_maxabs<<<2048, 256, 0, stream>>>((const uint4*)emb, flags, mab);
  k_tern_rows<<<4100, 1024, 0, stream>>>(Wih, Whh, fcw, flags, wim, whm, fcm);
  k_embed<<<32768, 1024, 0, stream>>>(text, emb, flags, mab, x0);
  // layer-0 input gemm (x0 consumed; region then reused as layer-0 x-out)
  k_bitgemm<<<dim3(512, 4), 256, 0, stream>>>(x0, wim, nbuf);
  // fused pipeline: layer-0 recur || layer-1 bitgemm || layer-1 recur
  k_pipe<<<192, 1024, 0, stream>>>(nbuf, x0, wim, whm, bih, bhh, flags,
                                   flagsA, flagsB, hidm);
  k_fc<<<128, 64, 0, stream>>>(hidm, fcm, flags, d_out);
}

// Round 2
// 1508.791 us; speedup vs baseline: 1.3859x; 1.2460x over previous
//
#include <hip/hip_runtime.h>
#include <cstdint>
#include <cstddef>

// ---------------------------------------------------------------------------
// QRNN 2-bit forward, exact ternary-integer formulation.
// flags[0]=1 -> floats are f32 (else bf16); flags[1]=1 -> text is int64.
// Ternary vectors (len 1024) bit-packed as 32 u64: [2i]=plus, [2i+1]=nonzero.
// As uint4 i: (p.lo, p.hi, z.lo, z.hi) for elements 64i..64i+63.
// dot: both=hz&wz; neg=both&(hp^wp); k=popc(both)-2*popc(neg)
// Decision v = k*0.1+bias vs +-0.5 is monotone in k -> precomputed integer
// thresholds kp/km reproduce the f64 predicate bit-exactly.
//
// R-pipeline (k_pipe, 192 blocks = 64 A + 64 B + 64 C):
//   A = layer-0 recur (produces x_t), B = layer-1 input bit-GEMM (x_t -> n_t,
//   in-place into nbuf), C = layer-1 recur (consumes n_t).
// R2 protocol — FENCELESS handoff (R1's RELEASE/agent stores emitted
// buffer_wbl2 + vmcnt(0) drains every step => 2x step-time; WRITE_SIZE 76MB):
//   * ALL cross-stage data stores/loads are RELAXED+AGENT scope (sc0 sc1:
//     write-through / read-through the Infinity Cache; never dirty in any
//     per-XCD L2 => no wbl2 ever needed).
//   * Flags are RELAXED agent stores issued AFTER __syncthreads(): the
//     barrier's vmcnt(0) drain (explicit asm waitcnt added too) guarantees
//     every wave's IC stores are globally visible before the flag store
//     issues. Consumer data loads are control-dependent on the observed flag
//     value => ordered without acquire fences (same mechanism as R1, passed).
//   * Same-address flag stores are separated by barrier drains => in-order.
//   * A defers its x_t store to the top of step t+1 (value in registers), so
//     the IC ack hides under the dot; flagsA=f means x[0..f-1] committed.
// Lags are constant (B ~= A-2 steps, C ~= A-4); pipeline rate = A's rate.
// Dependency graph acyclic (A never waits); 192 blocks x 16 waves @ 1
// block/CU all co-resident on 256 CUs => no deadlock (and correctness never
// depends on block->XCD placement; only IC-level visibility is assumed).
// nbuf aliasing: B writes slot (b,t) only after flagsA >= t+1 (A past step
// t+1's barrier, its furthest nbuf read is slot t+2, consumed at step t+2).
//
// k_recur-core design (stages A/C): weights live in VGPRs/AGPRs (64 words x
// 1024 threads = 256 KB/CU); h broadcast via same-address ds_read_b128.
// __launch_bounds__(1024,4) => 1 block/CU => 128-VGPR cap: REQUIRED so the
// 64 weight words stay in the register file (no scratch spill).
// ---------------------------------------------------------------------------

#define DRAIN_VMEM() asm volatile("s_waitcnt vmcnt(0)" ::: "memory")

static __device__ __forceinline__ float bf2f(unsigned short b) {
  return __uint_as_float(((unsigned)b) << 16);
}
static __device__ __forceinline__ unsigned short f2bf(float f) {
  unsigned u = __float_as_uint(f);
  u = (u + 0x7FFFu + ((u >> 16) & 1u)) >> 16;  // RNE
  return (unsigned short)u;
}
static __device__ __forceinline__ float loadw(const void* p, size_t i, int isf32) {
  return isf32 ? ((const float*)p)[i] : bf2f(((const unsigned short*)p)[i]);
}

__global__ __launch_bounds__(256) void k_detect(const unsigned short* __restrict__ embu,
                                                const int* __restrict__ text,
                                                int* __restrict__ flags) {
  int i = blockIdx.x * 256 + threadIdx.x;  // 65536 u16 samples: valid in either layout
  unsigned e = (embu[i] >> 7) & 0xFFu;     // bf16-view exponent field
  unsigned long long b = __ballot(e >= 127u);
  if ((threadIdx.x & 63) == 0 && b) atomicOr(&flags[0], 1);
  if (blockIdx.x == 0 && threadIdx.x == 0) {
    int allz = 1;
    for (int j = 0; j < 32; j++)
      if (text[2 * j + 1] != 0) allz = 0;   // first 256 B: valid in either layout
    flags[1] = allz;
  }
}

// vectorized max|emb|
__global__ __launch_bounds__(256) void k_maxabs(const uint4* __restrict__ w,
                                                const int* __restrict__ flags,
                                                unsigned* __restrict__ out) {
  int isf32 = flags[0];
  int n16 = isf32 ? 7680000 : 3840000;  // 30720000 elems / (4 or 8 per uint4)
  float mf = 0.f;
  unsigned mb = 0;
  int i = blockIdx.x * blockDim.x + threadIdx.x;
  int stride = gridDim.x * blockDim.x;
  if (isf32) {
    for (; i < n16; i += stride) {
      uint4 v = w[i];
      mf = fmaxf(mf, fabsf(__uint_as_float(v.x)));
      mf = fmaxf(mf, fabsf(__uint_as_float(v.y)));
      mf = fmaxf(mf, fabsf(__uint_as_float(v.z)));
      mf = fmaxf(mf, fabsf(__uint_as_float(v.w)));
    }
  } else {
    for (; i < n16; i += stride) {
      uint4 v = w[i];
      unsigned a;
      a = v.x & 0x7FFF7FFFu; mb = max(mb, a & 0xFFFFu); mb = max(mb, a >> 16);
      a = v.y & 0x7FFF7FFFu; mb = max(mb, a & 0xFFFFu); mb = max(mb, a >> 16);
      a = v.z & 0x7FFF7FFFu; mb = max(mb, a & 0xFFFFu); mb = max(mb, a >> 16);
      a = v.w & 0x7FFF7FFFu; mb = max(mb, a & 0xFFFFu); mb = max(mb, a >> 16);
    }
    mf = bf2f((unsigned short)mb);
  }
  for (int off = 32; off > 0; off >>= 1) mf = fmaxf(mf, __shfl_down(mf, off));
  __shared__ float red[4];
  if ((threadIdx.x & 63) == 0) red[threadIdx.x >> 6] = mf;
  __syncthreads();
  if (threadIdx.x == 0) {
    float b = fmaxf(fmaxf(red[0], red[1]), fmaxf(red[2], red[3]));
    atomicMax(out, __float_as_uint(b));  // b >= 0: bit pattern order-monotone
  }
}

__global__ __launch_bounds__(1024) void k_tern_rows(
    const void* __restrict__ Wih, const void* __restrict__ Whh,
    const void* __restrict__ fcw, const int* __restrict__ flags,
    unsigned long long* __restrict__ wim, unsigned long long* __restrict__ whm,
    unsigned long long* __restrict__ fcm) {
  int isf32 = flags[0];
  int b = blockIdx.x;  // 0..4099
  const void* src;
  size_t rowoff;
  unsigned long long* dst;
  if (b < 2048)      { src = Wih; rowoff = (size_t)b * 1024; dst = wim + (size_t)b * 32; }
  else if (b < 4096) { int r = b - 2048; src = Whh; rowoff = (size_t)r * 1024; dst = whm + (size_t)r * 32; }
  else               { int r = b - 4096; src = fcw; rowoff = (size_t)r * 1024; dst = fcm + (size_t)r * 32; }
  double w = (double)loadw(src, rowoff + threadIdx.x, isf32);
  unsigned long long bp = __ballot(w > 0.05);   // THR*W_SCALE, exact f64
  unsigned long long bm = __ballot(w < -0.05);
  if ((threadIdx.x & 63) == 0) {
    int wv = threadIdx.x >> 6;
    dst[2 * wv] = bp;
    dst[2 * wv + 1] = bp | bm;
  }
}

__global__ __launch_bounds__(1024) void k_embed(const int* __restrict__ text,
    const void* __restrict__ emb, const int* __restrict__ flags,
    const unsigned* __restrict__ mab, unsigned long long* __restrict__ x0) {
  int isf32 = flags[0], i64 = flags[1];
  int bt = blockIdx.x;
  long long tok = i64 ? ((const long long*)text)[bt] : (long long)text[bt];
  double ma = (double)__uint_as_float(*mab);
  float s = (float)exp2(ceil(log2(ma)));           // pow-2 scale (int_max = 1)
  float inv_s = 1.0f / s;                          // exact (pow-2)
  float w = loadw(emb, (size_t)tok * 1024 + threadIdx.x, isf32);
  float q = rintf(w * inv_s);                      // exact mul, half-even
  q = fminf(fmaxf(q, -2.0f), 1.0f);                // clip [-2, 1] (bw = 2)
  float val = q * s;                               // exact
  int code = (val > 0.5f) ? 1 : ((val < -0.5f) ? -1 : 0);
  unsigned long long bp = __ballot(code == 1);
  unsigned long long bm = __ballot(code == -1);
  if ((threadIdx.x & 63) == 0) {
    int wv = threadIdx.x >> 6;
    x0[(size_t)bt * 32 + 2 * wv] = bp;
    x0[(size_t)bt * 32 + 2 * wv + 1] = bp | bm;
  }
}

// ---- bit-GEMM (layer-0 pre-pass): n[bt][r] = <x_row[bt], Wi_row[r]> -------
__global__ __launch_bounds__(256, 4) void k_bitgemm(const unsigned long long* __restrict__ xm,
    const unsigned long long* __restrict__ wim, short* __restrict__ nbuf) {
  __shared__ __align__(16) uint4 lx[64 * 16];  // [bt][i] = (p.lo,p.hi,z.lo,z.hi)
  __shared__ unsigned any[64];
  int tid = threadIdx.x;
  int bt0 = blockIdx.x * 64;
  int r = blockIdx.y * 256 + tid;
  unsigned wplo[16], wphi[16], wzlo[16], wzhi[16];
  const uint4* wrow = (const uint4*)(wim + (size_t)r * 32);
#pragma unroll
  for (int i = 0; i < 16; i++) {
    uint4 w4 = wrow[i];
    wplo[i] = w4.x; wphi[i] = w4.y; wzlo[i] = w4.z; wzhi[i] = w4.w;
  }
  if (tid < 64) any[tid] = 0;
  __syncthreads();
  unsigned accor = 0;
#pragma unroll
  for (int i = 0; i < 4; i++) {
    int idx = tid * 4 + i;  // 0..1023 uint4 slots, straight copy
    uint4 v = ((const uint4*)(xm + (size_t)bt0 * 32))[idx];
    lx[idx] = v;
    accor |= v.z | v.w;  // nonzero-mask halves
  }
  if (accor) atomicOr(&any[tid >> 2], 1u);  // 4 threads per bt row
  __syncthreads();
  for (int bt = 0; bt < 64; bt++) {
    int k = 0;
    if (any[bt]) {
      const uint4* hx = lx + bt * 16;
      int sb = 0, sn = 0;
#pragma unroll
      for (int i = 0; i < 16; i++) {
        uint4 h = hx[i];  // broadcast ds_read_b128
        unsigned blo = h.z & wzlo[i];
        unsigned bhi = h.w & wzhi[i];
        unsigned nlo = (h.x ^ wplo[i]) & blo;
        unsigned nhi = (h.y ^ wphi[i]) & bhi;
        sb += __popc(blo) + __popc(bhi);
        sn += __popc(nlo) + __popc(nhi);
      }
      k = sb - 2 * sn;
    }
    nbuf[(size_t)(bt0 + bt) * 1024 + r] = (short)k;
  }
}

// ---- fused 3-stage pipeline ----------------------------------------------
#define FLAG_STRIDE 16  // one flag per 64 B to avoid line contention

static __device__ __forceinline__ int ldflag(const int* p) {
  return __hip_atomic_load(p, __ATOMIC_RELAXED, __HIP_MEMORY_SCOPE_AGENT);
}
static __device__ __forceinline__ void stflag(int* p, int v) {
  __hip_atomic_store(p, v, __ATOMIC_RELAXED, __HIP_MEMORY_SCOPE_AGENT);
}

// ROLE 0 = layer-0 recur (producer of x_t); ROLE 2 = layer-1 recur (consumer)
template <int ROLE>
static __device__ __forceinline__ void recur_stage(
    uint4 (*shb)[16], const short* nbuf,
    const unsigned long long* __restrict__ whm,
    const void* __restrict__ bih, const void* __restrict__ bhh,
    int isf32, int layer, int b, int r,
    unsigned long long* xrow,              // ROLE 0 only
    int* flagsA, int* flagsB,
    unsigned long long* __restrict__ hidm) {
  unsigned wplo[16], wphi[16], wzlo[16], wzhi[16];
  const uint4* wrow = (const uint4*)(whm + (size_t)(layer * 1024 + r) * 32);
#pragma unroll
  for (int i = 0; i < 16; i++) {
    uint4 w4 = wrow[i];
    wplo[i] = w4.x; wphi[i] = w4.y; wzlo[i] = w4.z; wzhi[i] = w4.w;
  }
  size_t boff = (size_t)layer * 1024 + r;
  double bias = (double)loadw(bih, boff, isf32) + (double)loadw(bhh, boff, isf32);
  // exact integer thresholds reproducing the f64 predicate
  int kp = (int)ceil((0.5 - bias) * 10.0);
  while ((double)kp * 0.1 + bias <= 0.5) kp++;
  while ((double)(kp - 1) * 0.1 + bias > 0.5) kp--;
  int km = (int)floor((-0.5 - bias) * 10.0);
  while ((double)km * 0.1 + bias >= -0.5) km--;
  while ((double)(km + 1) * 0.1 + bias < -0.5) km++;

  if (r < 32) ((unsigned long long*)shb)[r] = 0;  // zero buffer 0
  const short* nrow = nbuf + (size_t)b * 512 * 1024 + r;
  int wv = r >> 6;
  bool l0 = (r & 63) == 0;
  int fl = 0;   // ROLE 2: cached flagsB
  int nin;
  if (ROLE == 0) {
    nin = (int)nrow[0];  // t = 0 preload (pre-pass bitgemm data: plain load ok)
  } else {
    while ((fl = ldflag(flagsB + b * FLAG_STRIDE)) < 1) {}
    // data load control-dependent on flag value => ordered, no acquire needed
    nin = (int)__hip_atomic_load(nrow, __ATOMIC_RELAXED, __HIP_MEMORY_SCOPE_AGENT);
  }
  __syncthreads();
  int pb = 0;
  unsigned long long plo = 0, phi = 0;  // ROLE 0, l0 lanes: deferred x words
  for (int t = 0; t < 512; t++) {
    if (ROLE == 0) {
      // deferred store of x_{t-1}: IC ack hides under this step's dot
      if (l0 && t > 0) {
        __hip_atomic_store(xrow + (size_t)(t - 1) * 32 + 2 * wv, plo,
                           __ATOMIC_RELAXED, __HIP_MEMORY_SCOPE_AGENT);
        __hip_atomic_store(xrow + (size_t)(t - 1) * 32 + 2 * wv + 1, phi,
                           __ATOMIC_RELAXED, __HIP_MEMORY_SCOPE_AGENT);
      }
    } else {
      if (t < 511 && fl < t + 2)  // one non-spin refresh; consumed mid-dot
        fl = ldflag(flagsB + b * FLAG_STRIDE);
    }
    const uint4* Hq = shb[pb];
    int sb = 0, sn = 0;
#pragma unroll
    for (int i = 0; i < 8; i++) {
      uint4 h = Hq[i];  // broadcast ds_read_b128
      unsigned blo = h.z & wzlo[i];
      unsigned bhi = h.w & wzhi[i];
      unsigned nlo = (h.x ^ wplo[i]) & blo;
      unsigned nhi = (h.y ^ wphi[i]) & bhi;
      sb += __popc(blo) + __popc(bhi);
      sn += __popc(nlo) + __popc(nhi);
    }
    // mid-dot: prefetch next-step input so its latency hides under iters 8..15
    int nin_next = 0;
    bool got = true;
    if (ROLE == 0) {
      if (t < 511) nin_next = (int)nrow[(size_t)(t + 1) * 1024];
    } else if (t < 511) {
      got = (fl >= t + 2);
      if (got)
        nin_next = (int)__hip_atomic_load(nrow + (size_t)(t + 1) * 1024,
                                          __ATOMIC_RELAXED, __HIP_MEMORY_SCOPE_AGENT);
    }
#pragma unroll
    for (int i = 8; i < 16; i++) {
      uint4 h = Hq[i];
      unsigned blo = h.z & wzlo[i];
      unsigned bhi = h.w & wzhi[i];
      unsigned nlo = (h.x ^ wplo[i]) & blo;
      unsigned nhi = (h.y ^ wphi[i]) & bhi;
      sb += __popc(blo) + __popc(bhi);
      sn += __popc(nlo) + __popc(nhi);
    }
    int k = nin + sb - 2 * sn;
    unsigned long long bp = __ballot(k >= kp);
    unsigned long long bm = __ballot(k <= km);
    unsigned long long bz = bp | bm;
    if (l0) {
      uint4 o;
      o.x = (unsigned)bp; o.y = (unsigned)(bp >> 32);
      o.z = (unsigned)bz; o.w = (unsigned)(bz >> 32);
      shb[pb ^ 1][wv] = o;
      plo = bp; phi = bz;  // defer global store to next step
    }
    if (ROLE == 2 && !got && t < 511) {  // cold path: pipeline fill only
      while ((fl = ldflag(flagsB + b * FLAG_STRIDE)) < t + 2) {}
      nin_next = (int)__hip_atomic_load(nrow + (size_t)(t + 1) * 1024,
                                        __ATOMIC_RELAXED, __HIP_MEMORY_SCOPE_AGENT);
    }
    if (ROLE == 0) DRAIN_VMEM();  // per-wave: x-stores IC-acked before barrier
    __syncthreads();
    // publish AFTER barrier: all waves' stores of x[<=t-1] globally visible.
    // relaxed store, no fence; consecutive same-address stores separated by
    // barrier drains => commit in order.
    if (ROLE == 0 && r == 0 && t > 0)
      stflag(flagsA + b * FLAG_STRIDE, t);
    pb ^= 1;
    nin = nin_next;
  }
  if (ROLE == 0) {  // commit x[511], then final publish
    if (l0) {
      __hip_atomic_store(xrow + (size_t)511 * 32 + 2 * wv, plo,
                         __ATOMIC_RELAXED, __HIP_MEMORY_SCOPE_AGENT);
      __hip_atomic_store(xrow + (size_t)511 * 32 + 2 * wv + 1, phi,
                         __ATOMIC_RELAXED, __HIP_MEMORY_SCOPE_AGENT);
    }
    DRAIN_VMEM();
    __syncthreads();
    if (r == 0) stflag(flagsA + b * FLAG_STRIDE, 512);
  }
  if (r < 16) {  // final h is in shb[pb]
    uint4 h = shb[pb][r];
    size_t ho = (size_t)(layer * 64 + b) * 32;
    hidm[ho + 2 * r]     = ((unsigned long long)h.y << 32) | h.x;
    hidm[ho + 2 * r + 1] = ((unsigned long long)h.w << 32) | h.z;
  }
}

__global__ __launch_bounds__(1024, 4) void k_pipe(
    short* nbuf, unsigned long long* x0,
    const unsigned long long* __restrict__ wim,
    const unsigned long long* __restrict__ whm,
    const void* __restrict__ bih, const void* __restrict__ bhh,
    const int* __restrict__ flags, int* flagsA, int* flagsB,
    unsigned long long* __restrict__ hidm) {
  __shared__ __align__(16) uint4 shb[2][16];
  int role = blockIdx.x % 3;  // interleave roles across XCDs
  int b = blockIdx.x / 3;
  int r = threadIdx.x;
  int isf32 = flags[0];
  if (role == 0) {
    recur_stage<0>(shb, nbuf, whm, bih, bhh, isf32, 0, b, r,
                   x0 + (size_t)b * 512 * 32, flagsA, flagsB, hidm);
  } else if (role == 1) {
    // ---- stage B: layer-1 input bit-GEMM, trailing A by ~2 steps ----------
    unsigned wplo[16], wphi[16], wzlo[16], wzhi[16];
    const uint4* wrow = (const uint4*)(wim + (size_t)(1024 + r) * 32);
#pragma unroll
    for (int i = 0; i < 16; i++) {
      uint4 w4 = wrow[i];
      wplo[i] = w4.x; wphi[i] = w4.y; wzlo[i] = w4.z; wzhi[i] = w4.w;
    }
    const unsigned long long* xsrc = x0 + (size_t)b * 512 * 32;
    short* nout = nbuf + (size_t)b * 512 * 1024 + r;
    int fa = 0;
    unsigned long long vcur = 0;
    if (r < 32) {  // prologue: x[0] (flag spin by loader half-wave only)
      while ((fa = ldflag(flagsA + b * FLAG_STRIDE)) < 1) {}
      vcur = __hip_atomic_load(xsrc + r, __ATOMIC_RELAXED, __HIP_MEMORY_SCOPE_AGENT);
    }
    for (int t = 0; t < 512; t++) {
      if (r < 32) ((unsigned long long*)(shb[t & 1]))[r] = vcur;
      __syncthreads();
      // issue next x load early: IC latency hides under the dot
      bool got = false;
      unsigned long long vnext = 0;
      if (r < 32 && t < 511) {
        if (fa < t + 2) fa = ldflag(flagsA + b * FLAG_STRIDE);
        if (fa >= t + 2) {
          vnext = __hip_atomic_load(xsrc + (size_t)(t + 1) * 32 + r,
                                    __ATOMIC_RELAXED, __HIP_MEMORY_SCOPE_AGENT);
          got = true;
        }
      }
      const uint4* hx = shb[t & 1];
      int sb = 0, sn = 0;
#pragma unroll
      for (int i = 0; i < 16; i++) {
        uint4 h = hx[i];  // broadcast ds_read_b128
        unsigned blo = h.z & wzlo[i];
        unsigned bhi = h.w & wzhi[i];
        unsigned nlo = (h.x ^ wplo[i]) & blo;
        unsigned nhi = (h.y ^ wphi[i]) & bhi;
        sb += __popc(blo) + __popc(bhi);
        sn += __popc(nlo) + __popc(nhi);
      }
      // write-through to IC (sc0 sc1): no dirty L2 line, no wbl2 ever
      __hip_atomic_store(nout + (size_t)t * 1024, (short)(sb - 2 * sn),
                         __ATOMIC_RELAXED, __HIP_MEMORY_SCOPE_AGENT);
      if (r < 32 && t < 511 && !got) {  // cold path: pipeline fill only
        while ((fa = ldflag(flagsA + b * FLAG_STRIDE)) < t + 2) {}
        vnext = __hip_atomic_load(xsrc + (size_t)(t + 1) * 32 + r,
                                  __ATOMIC_RELAXED, __HIP_MEMORY_SCOPE_AGENT);
      }
      DRAIN_VMEM();      // per-wave: n-stores IC-acked before barrier
      __syncthreads();
      if (r == 0) stflag(flagsB + b * FLAG_STRIDE, t + 1);  // after barrier
      vcur = vnext;
    }
  } else {
    recur_stage<2>(shb, nbuf, whm, bih, bhh, isf32, 1, b, r,
                   (unsigned long long*)0, flagsA, flagsB, hidm);
  }
}

__global__ __launch_bounds__(64) void k_fc(const unsigned long long* __restrict__ hidm,
    const unsigned long long* __restrict__ fcm, const int* __restrict__ flags,
    void* __restrict__ out) {
  int isf32 = flags[0];
  int lb = blockIdx.x, lane = threadIdx.x;
  unsigned long long hp = 0, hz = 0;
  if (lane < 16) {
    hp = hidm[lb * 32 + 2 * lane];
    hz = hidm[lb * 32 + 2 * lane + 1];
  }
#pragma unroll
  for (int o = 0; o < 4; o++) {
    int k = 0;
    if (lane < 16) {
      unsigned long long wp = fcm[o * 32 + 2 * lane], wz = fcm[o * 32 + 2 * lane + 1];
      unsigned long long both = hz & wz;
      unsigned long long neg = both & (hp ^ wp);
      k = __popcll(both) - 2 * __popcll(neg);
    }
    for (int off = 8; off > 0; off >>= 1) k += __shfl_down(k, off);
    if (lane == 0) {
      float v = (float)((double)k * 0.1);
      if (isf32) ((float*)out)[lb * 4 + o] = v;
      else       ((unsigned short*)out)[lb * 4 + o] = f2bf(v);
    }
  }
}

extern "C" void kernel_launch(void* const* d_in, const int* in_sizes, int n_in,
                              void* d_out, int out_size, void* d_ws, size_t ws_size,
                              hipStream_t stream) {
  (void)in_sizes; (void)n_in; (void)out_size; (void)ws_size;
  const int* text = (const int*)d_in[0];
  // d_in[1] text_lengths: unused by the reference
  const void* emb = d_in[2];
  const void* Wih = d_in[3];
  const void* Whh = d_in[4];
  const void* bih = d_in[5];
  const void* bhh = d_in[6];
  const void* fcw = d_in[7];

  // workspace layout (~73 MB)
  char* ws = (char*)d_ws;
  int* flags = (int*)(ws);
  unsigned* mab = (unsigned*)(ws + 64);
  int* flagsA = (int*)(ws + 1024);   // 64 flags, stride 16 ints (4 KB)
  int* flagsB = (int*)(ws + 5120);   // 64 flags, stride 16 ints (4 KB)
  size_t off = 16384;
  unsigned long long* x0 = (unsigned long long*)(ws + off);  off += (size_t)32768 * 256;
  unsigned long long* wim = (unsigned long long*)(ws + off); off += (size_t)2048 * 256;
  unsigned long long* whm = (unsigned long long*)(ws + off); off += (size_t)2048 * 256;
  unsigned long long* fcm = (unsigned long long*)(ws + off); off += (size_t)4 * 256;
  unsigned long long* hidm = (unsigned long long*)(ws + off); off += (size_t)128 * 256;
  short* nbuf = (short*)(ws + off);                          off += (size_t)32768 * 1024 * 2;

  hipMemsetAsync(ws, 0, 16384, stream);  // flags, mab, flagsA, flagsB
  k_detect<<<256, 256, 0, stream>>>((const unsigned short*)emb, text, flags);
  k_maxabs<<<2048, 256, 0, stream>>>((const uint4*)emb, flags, mab);
  k_tern_rows<<<4100, 1024, 0, stream>>>(Wih, Whh, fcw, flags, wim, whm, fcm);
  k_embed<<<32768, 1024, 0, stream>>>(text, emb, flags, mab, x0);
  // layer-0 input gemm (x0 consumed; region then reused as layer-0 x-out)
  k_bitgemm<<<dim3(512, 4), 256, 0, stream>>>(x0, wim, nbuf);
  // fused pipeline: layer-0 recur || layer-1 bitgemm || layer-1 recur
  k_pipe<<<192, 1024, 0, stream>>>(nbuf, x0, wim, whm, bih, bhh, flags,
                                   flagsA, flagsB, hidm);
  k_fc<<<128, 64, 0, stream>>>(hidm, fcm, flags, d_out);
}